// Round 10
// baseline (165.046 us; speedup 1.0000x reference)
//
#include <hip/hip_runtime.h>
#include <cstddef>

typedef __attribute__((ext_vector_type(8))) short bf16x8;
typedef __attribute__((ext_vector_type(4))) float f32x4;
typedef __attribute__((ext_vector_type(16))) float f32x16;
typedef unsigned short ushort_t;

namespace {
constexpr int Tt = 4, Hh = 44, Ww = 44, Cc = 384, NH = 12, HD = 32;
constexpr int NWIN = 25, NT = 400, NTP = 416, NPOS = Hh * Ww;
constexpr int NTOK = 2 * Tt * NPOS;                 // 15488 = 121*128
constexpr float SCALE = 0.17677669529663687f;       // 1/sqrt(32)
constexpr float LOG2E = 1.4426950408889634f;
constexpr size_t XN  = (size_t)NTOK * Cc;           // 5,947,392
constexpr size_t WN  = (size_t)3 * Cc * Cc;         // 442,368
constexpr size_t PWN = (size_t)Cc * Cc;             // 147,456
}

__device__ __forceinline__ ushort_t f2bf(float f) {
  unsigned u = __builtin_bit_cast(unsigned, f);
  u += 0x7fffu + ((u >> 16) & 1u);  // RNE
  return (ushort_t)(u >> 16);
}

__device__ __forceinline__ unsigned cvt_pk_bf16(float a, float b) {
  unsigned r;
  asm volatile("v_cvt_pk_bf16_f32 %0, %1, %2" : "=v"(r) : "v"(a), "v"(b));
  return r;  // lo16 = bf16(a), hi16 = bf16(b)
}

// async global->LDS, 16B per lane (used by proj)
__device__ __forceinline__ void gload16(const void* g, void* l) {
  __builtin_amdgcn_global_load_lds(
      (const __attribute__((address_space(1))) unsigned int*)g,
      (__attribute__((address_space(3))) unsigned int*)l, 16, 0, 0);
}

// D-layout f32x16 (32x32 mfma acc) -> two bf16x8 A/B-operand fragments
// (k-slices {8hi..8hi+7} and {16+8hi..}), via 8 cvt_pk + 4 permlane32_swap.
// Identical transform to the verified P^T relayout (R3+).
__device__ __forceinline__ void dlayout_to_frags(const float* e, bf16x8& f0,
                                                 bf16x8& f1) {
  unsigned w0 = cvt_pk_bf16(e[0], e[1]),   w1 = cvt_pk_bf16(e[2], e[3]);
  unsigned w2 = cvt_pk_bf16(e[4], e[5]),   w3 = cvt_pk_bf16(e[6], e[7]);
  unsigned w4 = cvt_pk_bf16(e[8], e[9]),   w5 = cvt_pk_bf16(e[10], e[11]);
  unsigned w6 = cvt_pk_bf16(e[12], e[13]), w7 = cvt_pk_bf16(e[14], e[15]);
  asm volatile("v_permlane32_swap_b32 %0, %1" : "+v"(w0), "+v"(w2));
  asm volatile("v_permlane32_swap_b32 %0, %1" : "+v"(w1), "+v"(w3));
  asm volatile("v_permlane32_swap_b32 %0, %1" : "+v"(w4), "+v"(w6));
  asm volatile("v_permlane32_swap_b32 %0, %1" : "+v"(w5), "+v"(w7));
  union { bf16x8 v; unsigned u[4]; } p0, p1;
  p0.u[0] = w0; p0.u[1] = w1; p0.u[2] = w2; p0.u[3] = w3;
  p1.u[0] = w4; p1.u[1] = w5; p1.u[2] = w6; p1.u[3] = w7;
  f0 = p0.v; f1 = p1.v;
}

// ---------------------------------------------------------------------------
// K0: fp32->bf16 conversion of qkv_w and proj_w only (x is consumed fp32 by
// the fused kernel; no planes exist anymore).
// ---------------------------------------------------------------------------
__global__ __launch_bounds__(256) void conv_w(
    const float* __restrict__ w1, const float* __restrict__ w2,
    ushort_t* __restrict__ w1o, ushort_t* __restrict__ w2o) {
  constexpr int WN8 = (int)(WN / 8), PN8 = (int)(PWN / 8);
  const int i = blockIdx.x * 256 + threadIdx.x;
  if (i >= WN8 + PN8) return;
  const float* s;
  ushort_t* d;
  int j;
  if (i < WN8) { s = w1; d = w1o; j = i; }
  else         { s = w2; d = w2o; j = i - WN8; }
  const float4* s4 = (const float4*)s;
  float4 a = s4[2 * j], bq = s4[2 * j + 1];
  union { bf16x8 v; unsigned u[4]; } o;
  o.u[0] = cvt_pk_bf16(a.x, a.y);   o.u[1] = cvt_pk_bf16(a.z, a.w);
  o.u[2] = cvt_pk_bf16(bq.x, bq.y); o.u[3] = cvt_pk_bf16(bq.z, bq.w);
  ((bf16x8*)d)[j] = o.v;
}

// ---------------------------------------------------------------------------
// K1: FUSED QKV-projection + windowed attention. One block per (window,head):
// 600 blocks x 832 threads (13 waves; wave w owns token/query tile w of 32).
//
// Phase A (GEMM): [416 gathered tokens] x [96 cols = Q|K|V of this head] x
//   K=384. tokOf[416] built once (invalid -> -1 -> zero rows = reference pad
//   semantics). x staged fp32->bf16 (cvt_pk) into XOR-swizzled LDS; weights
//   from bf16 wb. Swapped operands: D col = token. 6 MFMA/wave/K-step.
// Phase B (deposit): Q: acc*SCALE*LOG2E -> frags kept in REGISTERS (wave's
//   own tile). K: frags -> swizzled LDS rows. V: scalar bf16 -> swizzled
//   V^T LDS. LDS regions alias the GEMM staging buffers (barrier-separated).
// Phase C (attention): R9 structure — swapped QK^T from LDS K + reg Q,
//   no-max softmax (scores tiny), P relayout, PV with V^T, masked keys
//   400..415, output bf16 [token][384].
// ---------------------------------------------------------------------------
__global__ __launch_bounds__(832, 1) void fused_attn(
    const float* __restrict__ xf, const ushort_t* __restrict__ wb,
    ushort_t* __restrict__ aout) {
  // [0, 26624)            : Xs (GEMM x tile)   / K_lds (attn)
  // [26624, 26624+6144)   : Ws (GEMM w tile)   / Vt head (attn)
  // [26624, 55296)        : Vt = 32 rows x 896B
  __shared__ __align__(16) unsigned char smem[55296];
  __shared__ int tokOf[416];

  // XCD clustering: 600 % 8 == 0 -> each XCD gets 75 contiguous planes
  const int bid = blockIdx.x;
  const int wh = (bid & 7) * 75 + (bid >> 3);
  const int head = wh % NH, bw = wh / NH;
  const int b = bw / NWIN, win = bw % NWIN, hi5 = win / 5, wi5 = win % 5;

  const int tid = threadIdx.x, lane = tid & 63, wid = tid >> 6;
  const int l31 = lane & 31, hi = lane >> 5;

  // ---- token map (once) ----
  if (tid < NTP) {
    const int kk = tid;
    const int tt = kk / 100, rem = kk - tt * 100;
    const int hh = rem / 10, ww2 = rem - hh * 10;
    const int h = hi5 * 10 + hh, w = wi5 * 10 + ww2;
    const bool v = (kk < NT) && (h < Hh) && (w < Ww);
    tokOf[tid] = v ? ((b * Tt + tt) * NPOS + h * Ww + w) : -1;
  }
  __syncthreads();

  // ---- Phase A: QKV GEMM ----
  // staging assignment (fixed per thread): rows row0=tid>>2 and row1=row0+208,
  // 16B chunk ch = tid&3.
  const int row0 = tid >> 2, ch = tid & 3;
  const int row1 = row0 + 208;
  const int tok0 = tokOf[row0], tok1 = tokOf[row1];
  const float* xp0 = xf + (size_t)(tok0 < 0 ? 0 : tok0) * Cc + ch * 8;
  const float* xp1 = xf + (size_t)(tok1 < 0 ? 0 : tok1) * Cc + ch * 8;
  const unsigned xw0 = row0 * 64 + (((ch ^ (row0 >> 1)) & 3) << 4);
  const unsigned xw1 = row1 * 64 + (((ch ^ (row1 >> 1)) & 3) << 4);
  // weight staging: rows 0..95 <-> w-row block*384 + head*32 + (row&31)
  const ushort_t* wp = nullptr;
  unsigned wlofs = 0;
  if (tid < 384) {
    const int wrow = tid >> 2, wch = tid & 3;
    const int wgr = (wrow >> 5) * Cc + head * HD + (wrow & 31);
    wp = wb + (size_t)wgr * Cc + wch * 8;
    wlofs = 26624 + wrow * 64 + (((wch ^ (wrow >> 1)) & 3) << 4);
  }

  f32x16 accQ = {}, accK = {}, accV = {};
  const int br = wid * 32 + l31;          // this wave's token rows
  const unsigned bsz = (br >> 1) & 3;

  for (int kb = 0; kb < 12; ++kb) {
    if (kb) __syncthreads();
    {
      float4 a0 = {0.f, 0.f, 0.f, 0.f}, b0 = {0.f, 0.f, 0.f, 0.f};
      float4 a1 = {0.f, 0.f, 0.f, 0.f}, b1 = {0.f, 0.f, 0.f, 0.f};
      if (tok0 >= 0) {
        a0 = *(const float4*)(xp0 + kb * 32);
        b0 = *(const float4*)(xp0 + kb * 32 + 4);
      }
      if (tok1 >= 0) {
        a1 = *(const float4*)(xp1 + kb * 32);
        b1 = *(const float4*)(xp1 + kb * 32 + 4);
      }
      union { bf16x8 v; unsigned u[4]; } t0, t1;
      t0.u[0] = cvt_pk_bf16(a0.x, a0.y); t0.u[1] = cvt_pk_bf16(a0.z, a0.w);
      t0.u[2] = cvt_pk_bf16(b0.x, b0.y); t0.u[3] = cvt_pk_bf16(b0.z, b0.w);
      t1.u[0] = cvt_pk_bf16(a1.x, a1.y); t1.u[1] = cvt_pk_bf16(a1.z, a1.w);
      t1.u[2] = cvt_pk_bf16(b1.x, b1.y); t1.u[3] = cvt_pk_bf16(b1.z, b1.w);
      *(bf16x8*)(smem + xw0) = t0.v;
      *(bf16x8*)(smem + xw1) = t1.v;
      if (tid < 384) *(bf16x8*)(smem + wlofs) = *(const bf16x8*)(wp + kb * 32);
    }
    __syncthreads();

    const bf16x8 xf0 = *(const bf16x8*)(smem + br * 64 + ((hi ^ bsz) << 4));
    const bf16x8 xf1 =
        *(const bf16x8*)(smem + br * 64 + (((2 + hi) ^ bsz) << 4));
#pragma unroll
    for (int j = 0; j < 3; ++j) {
      const int ar = j * 32 + l31;
      const unsigned asz = (ar >> 1) & 3;
      const bf16x8 wf0 =
          *(const bf16x8*)(smem + 26624 + ar * 64 + ((hi ^ asz) << 4));
      const bf16x8 wf1 =
          *(const bf16x8*)(smem + 26624 + ar * 64 + (((2 + hi) ^ asz) << 4));
      f32x16* accp = j == 0 ? &accQ : (j == 1 ? &accK : &accV);
      *accp = __builtin_amdgcn_mfma_f32_32x32x16_bf16(wf0, xf0, *accp, 0, 0, 0);
      *accp = __builtin_amdgcn_mfma_f32_32x32x16_bf16(wf1, xf1, *accp, 0, 0, 0);
    }
  }

  // ---- Phase B: deposit ----
  __syncthreads();  // all frag reads of Xs/Ws done; safe to overwrite

  // Q -> registers (pre-scaled)
  bf16x8 qfa, qfb;
  {
    const float QS = SCALE * LOG2E;
    float e[16];
#pragma unroll
    for (int r = 0; r < 16; ++r) e[r] = accQ[r] * QS;
    dlayout_to_frags(e, qfa, qfb);
  }
  // K -> LDS rows [row][32d], 64B pitch, chunk^=(row>>1)&3
  {
    float e[16];
#pragma unroll
    for (int r = 0; r < 16; ++r) e[r] = accK[r];
    bf16x8 k0, k1;
    dlayout_to_frags(e, k0, k1);
    const int krow = wid * 32 + l31;
    const unsigned ks = (krow >> 1) & 3;
    *(bf16x8*)(smem + krow * 64 + ((hi ^ ks) << 4)) = k0;
    *(bf16x8*)(smem + krow * 64 + (((2 + hi) ^ ks) << 4)) = k1;
  }
  // V -> V^T LDS (pitch 896B, chunk^f(d)), 16 scalar bf16 per lane
  {
    const int key = wid * 32 + l31;
    const int kc = key >> 3, klo = key & 7;
#pragma unroll
    for (int r = 0; r < 16; ++r) {
      const int d = (r & 3) + 8 * (r >> 2) + 4 * hi;
      const int f = (d & 7) ^ ((d >> 3) & 3);
      *(ushort_t*)(smem + 26624 + d * 896 + ((kc ^ f) << 4) + klo * 2) =
          f2bf(accV[r]);
    }
  }
  __syncthreads();

  // ---- Phase C: attention (tile = wid) ----
  const int fv = (l31 & 7) ^ ((l31 >> 3) & 3);
  const unsigned char* vrow = smem + 26624 + l31 * 896;

  f32x16 o = {};
  float lpart = 0.f;

  for (int c = 0; c < 13; ++c) {
    const int row = c * 32 + l31;
    const unsigned rs = (row >> 1) & 3;
    const bf16x8 kf0 = *(const bf16x8*)(smem + row * 64 + ((hi ^ rs) << 4));
    const bf16x8 kf1 =
        *(const bf16x8*)(smem + row * 64 + (((2 + hi) ^ rs) << 4));

    f32x16 s = {};
    __builtin_amdgcn_s_setprio(1);
    s = __builtin_amdgcn_mfma_f32_32x32x16_bf16(kf0, qfa, s, 0, 0, 0);
    s = __builtin_amdgcn_mfma_f32_32x32x16_bf16(kf1, qfb, s, 0, 0, 0);
    __builtin_amdgcn_s_setprio(0);

    if (c == 12) {  // keys 400..415 = regs 8..15 -> excluded
#pragma unroll
      for (int r = 8; r < 16; ++r) s[r] = -1e30f;
    }

    float e[16];
#pragma unroll
    for (int r = 0; r < 16; ++r) e[r] = __builtin_amdgcn_exp2f(s[r]);
    lpart += ((e[0] + e[1]) + (e[2] + e[3])) + ((e[4] + e[5]) + (e[6] + e[7])) +
             (((e[8] + e[9]) + (e[10] + e[11])) +
              ((e[12] + e[13]) + (e[14] + e[15])));

    bf16x8 p0, p1;
    dlayout_to_frags(e, p0, p1);

    const bf16x8 vf0 = *(const bf16x8*)(vrow + (((4 * c + hi) ^ fv) << 4));
    const bf16x8 vf1 = *(const bf16x8*)(vrow + (((4 * c + 2 + hi) ^ fv) << 4));
    __builtin_amdgcn_s_setprio(1);
    o = __builtin_amdgcn_mfma_f32_32x32x16_bf16(vf0, p0, o, 0, 0, 0);
    o = __builtin_amdgcn_mfma_f32_32x32x16_bf16(vf1, p1, o, 0, 0, 0);
    __builtin_amdgcn_s_setprio(0);
  }

  lpart += __shfl_xor(lpart, 32);

  // ---- store bf16 to [token][384] ----
  {
    const int qrow = wid * 32 + l31;
    const int tokv = tokOf[qrow];
    if (tokv >= 0) {
      ushort_t* dst = aout + (size_t)tokv * Cc + head * HD;
      const float inv = 1.0f / lpart;
#pragma unroll
      for (int g4 = 0; g4 < 4; ++g4) {
        unsigned lo  = cvt_pk_bf16(o[4 * g4 + 0] * inv, o[4 * g4 + 1] * inv);
        unsigned hi2 = cvt_pk_bf16(o[4 * g4 + 2] * inv, o[4 * g4 + 3] * inv);
        uint2 st; st.x = lo; st.y = hi2;
        *(uint2*)(dst + 8 * g4 + 4 * hi) = st;
      }
    }
  }
}

// ---------------------------------------------------------------------------
// K2: projection GEMM [15488 x 384] @ [384 x 384]^T + bias -> fp32 out.
// m97 structure, swapped operands, float4 stores. (Unchanged.)
// ---------------------------------------------------------------------------
__global__ __launch_bounds__(256) void proj_mfma(
    const ushort_t* __restrict__ ab, const ushort_t* __restrict__ pw,
    const float* __restrict__ bias, float* __restrict__ out) {
  __shared__ __align__(16) unsigned char As[8192];
  __shared__ __align__(16) unsigned char Bs[8192];
  const int nt = blockIdx.x, mt = blockIdx.y;
  const int tid = threadIdx.x, lane = tid & 63, wid = tid >> 6;
  const int wm = wid >> 1, wn = wid & 1;
  const int g = lane >> 4, q = lane & 15;
  const int m0 = mt * 128, n0 = nt * 128;

  const unsigned char* aB = (const unsigned char*)ab;
  const unsigned char* wB = (const unsigned char*)pw;

  size_t aoff[2], boff[2];
  unsigned ldsoff[2];
#pragma unroll
  for (int p = 0; p < 2; ++p) {
    const int row = wid * 32 + p * 16 + (lane >> 2);
    const int gs = (lane & 3) ^ ((row >> 1) & 3);
    aoff[p] = (size_t)(m0 + row) * 768 + gs * 16;
    boff[p] = (size_t)(n0 + row) * 768 + gs * 16;
    ldsoff[p] = wid * 2048 + p * 1024;
  }

  f32x4 acc[4][4] = {};  // [i = N chunk][j = M chunk]

  for (int kb = 0; kb < 12; ++kb) {
    if (kb) __syncthreads();
#pragma unroll
    for (int p = 0; p < 2; ++p) {
      gload16(aB + aoff[p] + kb * 64, As + ldsoff[p]);
      gload16(wB + boff[p] + kb * 64, Bs + ldsoff[p]);
    }
    __syncthreads();
    bf16x8 tfr[4], wfr[4];
#pragma unroll
    for (int i = 0; i < 4; ++i) {
      const int ar = wm * 64 + i * 16 + q;
      tfr[i] = *(const bf16x8*)(As + ar * 64 + ((g ^ ((ar >> 1) & 3)) << 4));
      const int brr = wn * 64 + i * 16 + q;
      wfr[i] = *(const bf16x8*)(Bs + brr * 64 + ((g ^ ((brr >> 1) & 3)) << 4));
    }
#pragma unroll
    for (int i = 0; i < 4; ++i)
#pragma unroll
      for (int j = 0; j < 4; ++j)
        acc[i][j] = __builtin_amdgcn_mfma_f32_16x16x32_bf16(wfr[i], tfr[j],
                                                            acc[i][j], 0, 0, 0);
  }

#pragma unroll
  for (int j = 0; j < 4; ++j) {
    const int t = m0 + wm * 64 + j * 16 + q;
#pragma unroll
    for (int i = 0; i < 4; ++i) {
      const int col = n0 + wn * 64 + i * 16 + 4 * g;
      const float4 bb = *(const float4*)(bias + col);
      float4 st;
      st.x = acc[i][j][0] + bb.x;
      st.y = acc[i][j][1] + bb.y;
      st.z = acc[i][j][2] + bb.z;
      st.w = acc[i][j][3] + bb.w;
      *(float4*)(out + (size_t)t * Cc + col) = st;
    }
  }
}

// ---------------------------------------------------------------------------
extern "C" void kernel_launch(void* const* d_in, const int* in_sizes, int n_in,
                              void* d_out, int out_size, void* d_ws,
                              size_t ws_size, hipStream_t stream) {
  const float* x      = (const float*)d_in[0];
  const float* qkv_w  = (const float*)d_in[1];
  const float* proj_w = (const float*)d_in[2];
  const float* proj_b = (const float*)d_in[3];

  ushort_t* wb    = (ushort_t*)d_ws;      // [1152][384] bf16
  ushort_t* pwb   = wb + WN;              // [384][384] bf16
  ushort_t* attnb = pwb + PWN;            // [15488][384] bf16
  // total ~13 MB of d_ws

  constexpr int TOTW8 = (int)((WN + PWN) / 8);
  conv_w<<<(TOTW8 + 255) / 256, 256, 0, stream>>>(qkv_w, proj_w, wb, pwb);
  fused_attn<<<600, 832, 0, stream>>>(x, wb, attnb);
  proj_mfma<<<dim3(3, 121), 256, 0, stream>>>(attnb, pwb, proj_b,
                                              (float*)d_out);
}

// Round 11
// 88.015 us; speedup vs baseline: 1.8752x; 1.8752x over previous
//
#include <hip/hip_runtime.h>
#include <cstddef>

typedef __attribute__((ext_vector_type(8))) short bf16x8;
typedef __attribute__((ext_vector_type(4))) float f32x4;
typedef __attribute__((ext_vector_type(16))) float f32x16;
typedef unsigned short ushort_t;

namespace {
constexpr int Tt = 4, Hh = 44, Ww = 44, Cc = 384, NH = 12, HD = 32;
constexpr int NWIN = 25, NT = 400, NTP = 416, NPOS = Hh * Ww;
constexpr int NTOK = 2 * Tt * NPOS;                 // 15488 = 121*128
constexpr float SCALE = 0.17677669529663687f;       // 1/sqrt(32)
constexpr float LOG2E = 1.4426950408889634f;
constexpr size_t XN  = (size_t)NTOK * Cc;           // 5,947,392
constexpr size_t WN  = (size_t)3 * Cc * Cc;         // 442,368
constexpr size_t PWN = (size_t)Cc * Cc;             // 147,456
constexpr size_t PLN = (size_t)600 * NTP * HD;      // 7,987,200 per plane
}

__device__ __forceinline__ ushort_t f2bf(float f) {
  unsigned u = __builtin_bit_cast(unsigned, f);
  u += 0x7fffu + ((u >> 16) & 1u);  // RNE
  return (ushort_t)(u >> 16);
}

__device__ __forceinline__ unsigned cvt_pk_bf16(float a, float b) {
  unsigned r;
  asm volatile("v_cvt_pk_bf16_f32 %0, %1, %2" : "=v"(r) : "v"(a), "v"(b));
  return r;  // lo16 = bf16(a), hi16 = bf16(b)
}

// async global->LDS, 16B per lane; LDS dest = wave-uniform base + lane*16
__device__ __forceinline__ void gload16(const void* g, void* l) {
  __builtin_amdgcn_global_load_lds(
      (const __attribute__((address_space(1))) unsigned int*)g,
      (__attribute__((address_space(3))) unsigned int*)l, 16, 0, 0);
}

// ---------------------------------------------------------------------------
// K0: fp32->bf16 conversion of x, qkv_w, proj_w PLUS zero-fill of invalid /
// pad rows in the K and V windowed planes (reference semantics: padded
// positions contribute zero K rows (score 0 -> exp(0)=1 in the denominator)
// and zero V rows). Q plane needs no fill: invalid query outputs are never
// stored, and poison bf16 (0xAAAA ~ -3e-13) is numerically benign.
// ---------------------------------------------------------------------------
__global__ __launch_bounds__(256) void conv_all(
    const float* __restrict__ x, const float* __restrict__ w1,
    const float* __restrict__ w2, ushort_t* __restrict__ xo,
    ushort_t* __restrict__ w1o, ushort_t* __restrict__ w2o,
    ushort_t* __restrict__ kpl, ushort_t* __restrict__ vpl) {
  constexpr int XN8 = (int)(XN / 8), WN8 = (int)(WN / 8), PN8 = (int)(PWN / 8);
  constexpr int TOT8 = XN8 + WN8 + PN8;
  constexpr int ZTOT = 50 * NTP * NH;  // 249,600 (bw,kk,head) triples
  const int i = blockIdx.x * 256 + threadIdx.x;
  if (i < TOT8) {
    const float* s;
    ushort_t* d;
    int j;
    if (i < XN8)            { s = x;  d = xo;  j = i; }
    else if (i < XN8 + WN8) { s = w1; d = w1o; j = i - XN8; }
    else                    { s = w2; d = w2o; j = i - XN8 - WN8; }
    const float4* s4 = (const float4*)s;
    float4 a = s4[2 * j], bq = s4[2 * j + 1];
    union { bf16x8 v; ushort_t u[8]; } o;
    o.u[0] = f2bf(a.x);  o.u[1] = f2bf(a.y);  o.u[2] = f2bf(a.z);  o.u[3] = f2bf(a.w);
    o.u[4] = f2bf(bq.x); o.u[5] = f2bf(bq.y); o.u[6] = f2bf(bq.z); o.u[7] = f2bf(bq.w);
    ((bf16x8*)d)[j] = o.v;
  } else if (i < TOT8 + ZTOT) {
    const int j = i - TOT8;
    const int pair = j / NH, head = j - pair * NH;
    const int bw = pair / NTP, kk = pair - bw * NTP;
    const int win = bw % NWIN, hi5 = win / 5, wi5 = win % 5;
    bool fill;
    if (kk >= NT) {
      fill = true;
    } else {
      const int rem = kk % 100;
      const int hh = rem / 10, ww2 = rem - hh * 10;
      fill = (hi5 == 4 && hh >= 4) || (wi5 == 4 && ww2 >= 4);
    }
    if (fill) {
      const size_t off = ((size_t)(bw * NH + head) * NTP + kk) * HD;
      bf16x8 z;
      z[0]=0;z[1]=0;z[2]=0;z[3]=0;z[4]=0;z[5]=0;z[6]=0;z[7]=0;
#pragma unroll
      for (int p = 0; p < 4; ++p) {
        ((bf16x8*)(kpl + off))[p] = z;
        ((bf16x8*)(vpl + off))[p] = z;
      }
    }
  }
}

// ---------------------------------------------------------------------------
// K1: dense QKV GEMM [15488 x 384] @ [384 x 1152]^T, m97 structure (128x128
// tile, BK=32, global_load_lds 16B, pre-swizzled source). Linear grid 1089
// with bijective XCD-chunk swizzle (q=136, r=1): each XCD gets 136
// contiguous work items -> shared A-panels L2-resident. Epilogue: direct
// uint2 scatter to window planes (VGPR 28, occupancy ~67%). Q pre-scaled by
// SCALE*LOG2E.
// ---------------------------------------------------------------------------
__global__ __launch_bounds__(256) void qkv_mfma(
    const ushort_t* __restrict__ xb, const ushort_t* __restrict__ wb,
    ushort_t* __restrict__ qpl, ushort_t* __restrict__ kpl,
    ushort_t* __restrict__ vpl) {
  __shared__ __align__(16) unsigned char As[8192];
  __shared__ __align__(16) unsigned char Bs[8192];
  // bijective XCD-chunk swizzle over 1089 work items (q=136, r=1)
  const unsigned bid = blockIdx.x;
  const unsigned xcd = bid & 7u, slot = bid >> 3;
  const unsigned wgid = (xcd == 0 ? 0u : 137u + (xcd - 1u) * 136u) + slot;
  const int nt = wgid % 9, mt = wgid / 9;
  const int tid = threadIdx.x, lane = tid & 63, wid = tid >> 6;
  const int wm = wid >> 1, wn = wid & 1;
  const int g = lane >> 4, q = lane & 15;
  const int m0 = mt * 128, n0 = nt * 128;

  const unsigned char* xB = (const unsigned char*)xb;
  const unsigned char* wB = (const unsigned char*)wb;

  size_t aoff[2], boff[2];
  unsigned ldsoff[2];
#pragma unroll
  for (int p = 0; p < 2; ++p) {
    const int row = wid * 32 + p * 16 + (lane >> 2);
    const int gs = (lane & 3) ^ ((row >> 1) & 3);
    aoff[p] = (size_t)(m0 + row) * 768 + gs * 16;
    boff[p] = (size_t)(n0 + row) * 768 + gs * 16;
    ldsoff[p] = wid * 2048 + p * 1024;
  }

  f32x4 acc[4][4] = {};  // [i = N chunk][j = M chunk]

  for (int kb = 0; kb < 12; ++kb) {
    if (kb) __syncthreads();
#pragma unroll
    for (int p = 0; p < 2; ++p) {
      gload16(xB + aoff[p] + kb * 64, As + ldsoff[p]);
      gload16(wB + boff[p] + kb * 64, Bs + ldsoff[p]);
    }
    __syncthreads();
    bf16x8 tfr[4], wfr[4];
#pragma unroll
    for (int i = 0; i < 4; ++i) {
      const int ar = wm * 64 + i * 16 + q;  // token rows
      tfr[i] = *(const bf16x8*)(As + ar * 64 + ((g ^ ((ar >> 1) & 3)) << 4));
      const int br = wn * 64 + i * 16 + q;  // weight rows
      wfr[i] = *(const bf16x8*)(Bs + br * 64 + ((g ^ ((br >> 1) & 3)) << 4));
    }
#pragma unroll
    for (int i = 0; i < 4; ++i)
#pragma unroll
      for (int j = 0; j < 4; ++j)
        acc[i][j] = __builtin_amdgcn_mfma_f32_16x16x32_bf16(wfr[i], tfr[j],
                                                            acc[i][j], 0, 0, 0);
  }

  const float QS = SCALE * LOG2E;
#pragma unroll
  for (int j = 0; j < 4; ++j) {
    const int t = m0 + wm * 64 + j * 16 + q;  // token id (< 15488, guard-free)
    const int bt = t / NPOS, pos = t - bt * NPOS;
    const int h = pos / Ww, w = pos - h * Ww;
    const int b = bt >> 2, tt = bt & 3;
    const int hq = h / 10, wq = w / 10;
    const int kk = tt * 100 + (h - hq * 10) * 10 + (w - wq * 10);
    const int bw = b * NWIN + hq * 5 + wq;
#pragma unroll
    for (int i = 0; i < 4; ++i) {
      const int col = n0 + wn * 64 + i * 16 + 4 * g;
      const int which = col / Cc;
      const int head = (col - which * Cc) >> 5;
      const int d4 = col & 31;
      ushort_t* pl = which == 0 ? qpl : (which == 1 ? kpl : vpl);
      const float scl = which == 0 ? QS : 1.0f;
      uint2 st;
      st.x = cvt_pk_bf16(acc[i][j][0] * scl, acc[i][j][1] * scl);
      st.y = cvt_pk_bf16(acc[i][j][2] * scl, acc[i][j][3] * scl);
      *(uint2*)(pl + ((size_t)(bw * NH + head) * NTP + kk) * HD + d4) = st;
    }
  }
}

// ---------------------------------------------------------------------------
// K2: attention on contiguous per-(bw,head) planes. 600 blocks x 448 thr
// (7 waves): 4 blocks/CU (LDS 28KB, 28 waves/CU) -> all 600 blocks fit in
// ONE co-resident round (capacity 1024): no inter-CU scheduling tail.
// Each wave walks query tiles {wid, wid+7} sequentially; V^T staged once in
// swizzled LDS, shared by both passes; K L1-resident on the second pass.
// Q read linearly from its window plane (no decode in the loop). Swapped
// QK^T, no-max in-register softmax, cvt_pk+permlane P relayout, setprio (T5).
// ---------------------------------------------------------------------------
__global__ __launch_bounds__(448) void attn_mfma(
    const ushort_t* __restrict__ qpl, const ushort_t* __restrict__ kpl,
    const ushort_t* __restrict__ vpl, ushort_t* __restrict__ aout) {
  __shared__ __align__(16) unsigned char Vt[32 * 896];

  const int wh = blockIdx.x;                   // plane index = bw*12+head
  const int head = wh % NH, bw = wh / NH;
  const int b = bw / NWIN, win = bw % NWIN, hi5 = win / 5, wi5 = win % 5;

  const int tid = threadIdx.x, lane = tid & 63, wid = tid >> 6;
  const int l31 = lane & 31, hi = lane >> 5;

  const ushort_t* qbase = qpl + (size_t)wh * (NTP * HD);
  const ushort_t* kbase = kpl + (size_t)wh * (NTP * HD);
  const ushort_t* vbase = vpl + (size_t)wh * (NTP * HD);

  // ---- stage V^T (contiguous reads; transposed swizzled writes) ----
  for (int slot = tid; slot < 1664; slot += 448) {
    const int key = slot >> 2, dblk = (slot & 3) * 8;
    union { bf16x8 v; ushort_t u[8]; } t;
    t.v = *(const bf16x8*)(vbase + (size_t)key * HD + dblk);
    const int kc = key >> 3, klo = key & 7;
#pragma unroll
    for (int j = 0; j < 8; ++j) {
      const int d = dblk + j;
      const int f = (d & 7) ^ ((d >> 3) & 3);
      *(ushort_t*)(Vt + d * 896 + ((kc ^ f) << 4) + klo * 2) = t.u[j];
    }
  }
  __syncthreads();

  const int fv = (l31 & 7) ^ ((l31 >> 3) & 3);  // V^T read swizzle for d=l31
  const unsigned char* vrow = Vt + l31 * 896;

  for (int tile = wid; tile < 13; tile += 7) {
    const int qrow = tile * 32 + l31;            // 0..415
    const ushort_t* qp = qbase + (size_t)qrow * HD;
    const bf16x8 qfa = *(const bf16x8*)(qp + hi * 8);
    const bf16x8 qfb = *(const bf16x8*)(qp + 16 + hi * 8);

    unsigned koff = (unsigned)l31 * HD;
    bf16x8 kf0 = *(const bf16x8*)(kbase + koff + hi * 8);
    bf16x8 kf1 = *(const bf16x8*)(kbase + koff + 16 + hi * 8);

    f32x16 o = {};
    float lpart = 0.f;

    for (int c = 0; c < 13; ++c) {
      f32x16 s = {};
      __builtin_amdgcn_s_setprio(1);
      s = __builtin_amdgcn_mfma_f32_32x32x16_bf16(kf0, qfa, s, 0, 0, 0);
      s = __builtin_amdgcn_mfma_f32_32x32x16_bf16(kf1, qfb, s, 0, 0, 0);
      __builtin_amdgcn_s_setprio(0);

      if (c < 12) {  // prefetch next chunk (planes padded to 416 rows)
        koff += 32u * HD;
        kf0 = *(const bf16x8*)(kbase + koff + hi * 8);
        kf1 = *(const bf16x8*)(kbase + koff + 16 + hi * 8);
      }

      if (c == 12) {  // keys 400..415 = tile rows 16..31 = regs 8..15 -> p=0
#pragma unroll
        for (int r = 8; r < 16; ++r) s[r] = -1e30f;
      }

      // ---- p = exp2(s) (no max subtraction), partial denominator ----
      float e[16];
#pragma unroll
      for (int r = 0; r < 16; ++r) e[r] = __builtin_amdgcn_exp2f(s[r]);
      lpart += ((e[0] + e[1]) + (e[2] + e[3])) + ((e[4] + e[5]) + (e[6] + e[7])) +
               (((e[8] + e[9]) + (e[10] + e[11])) +
                ((e[12] + e[13]) + (e[14] + e[15])));

      // ---- P^T -> bf16 B-frags (cvt_pk + permlane32_swap) ----
      unsigned w0 = cvt_pk_bf16(e[0], e[1]),   w1 = cvt_pk_bf16(e[2], e[3]);
      unsigned w2 = cvt_pk_bf16(e[4], e[5]),   w3 = cvt_pk_bf16(e[6], e[7]);
      unsigned w4 = cvt_pk_bf16(e[8], e[9]),   w5 = cvt_pk_bf16(e[10], e[11]);
      unsigned w6 = cvt_pk_bf16(e[12], e[13]), w7 = cvt_pk_bf16(e[14], e[15]);
      asm volatile("v_permlane32_swap_b32 %0, %1" : "+v"(w0), "+v"(w2));
      asm volatile("v_permlane32_swap_b32 %0, %1" : "+v"(w1), "+v"(w3));
      asm volatile("v_permlane32_swap_b32 %0, %1" : "+v"(w4), "+v"(w6));
      asm volatile("v_permlane32_swap_b32 %0, %1" : "+v"(w5), "+v"(w7));
      union { bf16x8 v; unsigned u[4]; } p0, p1;
      p0.u[0] = w0; p0.u[1] = w1; p0.u[2] = w2; p0.u[3] = w3;
      p1.u[0] = w4; p1.u[1] = w5; p1.u[2] = w6; p1.u[3] = w7;

      // ---- PV: O^T += V^T @ P^T ----
      const bf16x8 vf0 = *(const bf16x8*)(vrow + (((4 * c + hi) ^ fv) << 4));
      const bf16x8 vf1 = *(const bf16x8*)(vrow + (((4 * c + 2 + hi) ^ fv) << 4));
      __builtin_amdgcn_s_setprio(1);
      o = __builtin_amdgcn_mfma_f32_32x32x16_bf16(vf0, p0.v, o, 0, 0, 0);
      o = __builtin_amdgcn_mfma_f32_32x32x16_bf16(vf1, p1.v, o, 0, 0, 0);
      __builtin_amdgcn_s_setprio(0);
    }

    lpart += __shfl_xor(lpart, 32);

    // ---- epilogue: normalize, store bf16 to [token][384] ----
    {
      const int tt = qrow / 100, rem = qrow - tt * 100;
      const int hh = rem / 10, ww2 = rem - hh * 10;
      const int h = hi5 * 10 + hh, w = wi5 * 10 + ww2;
      if (qrow < NT && h < Hh && w < Ww) {
        const int qtok = (b * Tt + tt) * NPOS + h * Ww + w;
        ushort_t* dst = aout + (size_t)qtok * Cc + head * HD;
        const float inv = 1.0f / lpart;
#pragma unroll
        for (int g4 = 0; g4 < 4; ++g4) {
          unsigned lo  = cvt_pk_bf16(o[4 * g4 + 0] * inv, o[4 * g4 + 1] * inv);
          unsigned hi2 = cvt_pk_bf16(o[4 * g4 + 2] * inv, o[4 * g4 + 3] * inv);
          uint2 st; st.x = lo; st.y = hi2;
          *(uint2*)(dst + 8 * g4 + 4 * hi) = st;
        }
      }
    }
  }
}

// ---------------------------------------------------------------------------
// K3: projection GEMM [15488 x 384] @ [384 x 384]^T + bias -> fp32 out.
// Swapped operands: D-rows = 4 consecutive N-cols -> float4 stores.
// ---------------------------------------------------------------------------
__global__ __launch_bounds__(256) void proj_mfma(
    const ushort_t* __restrict__ ab, const ushort_t* __restrict__ pw,
    const float* __restrict__ bias, float* __restrict__ out) {
  __shared__ __align__(16) unsigned char As[8192];
  __shared__ __align__(16) unsigned char Bs[8192];
  const int nt = blockIdx.x, mt = blockIdx.y;
  const int tid = threadIdx.x, lane = tid & 63, wid = tid >> 6;
  const int wm = wid >> 1, wn = wid & 1;
  const int g = lane >> 4, q = lane & 15;
  const int m0 = mt * 128, n0 = nt * 128;

  const unsigned char* aB = (const unsigned char*)ab;
  const unsigned char* wB = (const unsigned char*)pw;

  size_t aoff[2], boff[2];
  unsigned ldsoff[2];
#pragma unroll
  for (int p = 0; p < 2; ++p) {
    const int row = wid * 32 + p * 16 + (lane >> 2);
    const int gs = (lane & 3) ^ ((row >> 1) & 3);
    aoff[p] = (size_t)(m0 + row) * 768 + gs * 16;
    boff[p] = (size_t)(n0 + row) * 768 + gs * 16;
    ldsoff[p] = wid * 2048 + p * 1024;
  }

  f32x4 acc[4][4] = {};  // [i = N chunk][j = M chunk]

  for (int kb = 0; kb < 12; ++kb) {
    if (kb) __syncthreads();
#pragma unroll
    for (int p = 0; p < 2; ++p) {
      gload16(aB + aoff[p] + kb * 64, As + ldsoff[p]);
      gload16(wB + boff[p] + kb * 64, Bs + ldsoff[p]);
    }
    __syncthreads();
    bf16x8 tfr[4], wfr[4];
#pragma unroll
    for (int i = 0; i < 4; ++i) {
      const int ar = wm * 64 + i * 16 + q;
      tfr[i] = *(const bf16x8*)(As + ar * 64 + ((g ^ ((ar >> 1) & 3)) << 4));
      const int br = wn * 64 + i * 16 + q;
      wfr[i] = *(const bf16x8*)(Bs + br * 64 + ((g ^ ((br >> 1) & 3)) << 4));
    }
#pragma unroll
    for (int i = 0; i < 4; ++i)
#pragma unroll
      for (int j = 0; j < 4; ++j)
        acc[i][j] = __builtin_amdgcn_mfma_f32_16x16x32_bf16(wfr[i], tfr[j],
                                                            acc[i][j], 0, 0, 0);
  }

#pragma unroll
  for (int j = 0; j < 4; ++j) {
    const int t = m0 + wm * 64 + j * 16 + q;
#pragma unroll
    for (int i = 0; i < 4; ++i) {
      const int col = n0 + wn * 64 + i * 16 + 4 * g;
      const float4 bb = *(const float4*)(bias + col);
      float4 st;
      st.x = acc[i][j][0] + bb.x;
      st.y = acc[i][j][1] + bb.y;
      st.z = acc[i][j][2] + bb.z;
      st.w = acc[i][j][3] + bb.w;
      *(float4*)(out + (size_t)t * Cc + col) = st;
    }
  }
}

// ---------------------------------------------------------------------------
extern "C" void kernel_launch(void* const* d_in, const int* in_sizes, int n_in,
                              void* d_out, int out_size, void* d_ws,
                              size_t ws_size, hipStream_t stream) {
  const float* x      = (const float*)d_in[0];
  const float* qkv_w  = (const float*)d_in[1];
  const float* proj_w = (const float*)d_in[2];
  const float* proj_b = (const float*)d_in[3];

  ushort_t* xb    = (ushort_t*)d_ws;      // [15488][384] bf16
  ushort_t* wb    = xb + XN;              // [1152][384] bf16
  ushort_t* pwb   = wb + WN;              // [384][384] bf16
  ushort_t* qpl   = pwb + PWN;            // [600][416][32] bf16 planes
  ushort_t* kpl   = qpl + PLN;
  ushort_t* vpl   = kpl + PLN;
  ushort_t* attnb = vpl + PLN;            // [15488][384] bf16
  // total ~73 MB of d_ws

  constexpr int TOT8 = (int)((XN + WN + PWN) / 8);
  constexpr int ZTOT = 50 * NTP * NH;
  conv_all<<<(TOT8 + ZTOT + 255) / 256, 256, 0, stream>>>(
      x, qkv_w, proj_w, xb, wb, pwb, kpl, vpl);
  qkv_mfma<<<1089, 256, 0, stream>>>(xb, wb, qpl, kpl, vpl);
  attn_mfma<<<600, 448, 0, stream>>>(qpl, kpl, vpl, attnb);
  proj_mfma<<<dim3(3, 121), 256, 0, stream>>>(attnb, pwb, proj_b, (float*)d_out);
}